// Round 10
// baseline (682.621 us; speedup 1.0000x reference)
//
#include <hip/hip_runtime.h>
#include <cstddef>
#include <cstdint>

#define NB 8
#define NTHREADS 640        // 8 gate waves + 2 theta/RK4 waves
#define HID 128
#define LIFT 32
#define NSP 13
#define NTH 19

typedef __attribute__((ext_vector_type(8))) short short8;
typedef __attribute__((ext_vector_type(4))) float f32x4;

// Packed per-row theta indices for the tridiagonal reaction matrix A(theta):
//   row j: cA = th[kA], cB = -(th[kB1]+th[kB2]), cC = th[kC]
// 5 bits each: kA | kB1<<5 | kB2<<10 | kC<<15. Index 19 = S.theta pad == 0.
// Table indexed by j+1 (virtual rows -1 and 13 are all-pad -> zero row).
// R6-R8 FAILED because row j=11 had kC=19 (pad) instead of 18 — the kr12*M
// coupling into dL was dropped (absmax 1.31 both rounds, same root cause).
// Now verified entry-by-entry against R2's hardware-verified c_k* tables.
#define PKI(a,b,c,d) ((uint32_t)(a)|((uint32_t)(b)<<5)|((uint32_t)(c)<<10)|((uint32_t)(d)<<15))
__device__ const uint32_t c_pk2[15] = {
  PKI(19,19,19,19),                     // j=-1 (pad)
  PKI(19, 0,19,12), PKI( 0,12, 1,19), PKI( 1, 2,19,13), PKI( 2,13, 3,19),
  PKI( 3, 4,19,14), PKI( 4,14, 5,19), PKI( 5, 6,19,15), PKI( 6,15, 7,19),
  PKI( 7, 8,19,16), PKI( 8,16, 9,19), PKI( 9,10,19,17), PKI(10,17,11,18),
  PKI(11,18,19,19),                     // j=12
  PKI(19,19,19,19)                      // j=13 (pad)
};

__device__ __forceinline__ uint32_t pk(float a, float b) {
  uint32_t ua = __float_as_uint(a), ub = __float_as_uint(b);
  ua = (ua + 0x7FFFu + ((ua >> 16) & 1u)) >> 16;
  ub = (ub + 0x7FFFu + ((ub >> 16) & 1u)) >> 16;
  return ua | (ub << 16);
}
__device__ __forceinline__ float sigm(float a) { return 1.f/(1.f + __expf(-a)); }
__device__ __forceinline__ float bperm(int addr, float v) {
  return __int_as_float(__builtin_amdgcn_ds_bpermute(addr, __float_as_int(v)));
}

// LDS-only barrier: drain this wave's LDS ops, then s_barrier. Does NOT wait
// vmcnt(0): global output stores / prefetch loads stay in flight across it.
__device__ __forceinline__ void sync_lds() {
  __builtin_amdgcn_sched_barrier(0);
  asm volatile("s_waitcnt lgkmcnt(0)" ::: "memory");
  __builtin_amdgcn_s_barrier();
  __builtin_amdgcn_sched_barrier(0);
}

union FragU { uint4 u; short8 s; };
// pack 8 consecutive floats into a bf16 short8 fragment (register-resident)
__device__ __forceinline__ short8 ldfrag(const float* p) {
  FragU t;
  const float4 a = *reinterpret_cast<const float4*>(p);
  const float4 b = *reinterpret_cast<const float4*>(p+4);
  t.u = make_uint4(pk(a.x,a.y), pk(a.z,a.w), pk(b.x,b.y), pk(b.z,b.w));
  return t.s;
}

// Weights (w_hh, W_head) stay in LDS as swizzled MFMA A-frags (84-VGPR cap:
// R1/R3/R4 all confirmed persistent sets past ~84 spill to scratch).
// W_lift/b_lift/b_head also in LDS (frees ~28 VGPRs for the polynomial-RK4
// temporaries). RK4 neighbor exchange via ds_bpermute (register operand).
struct Smem {
  uint32_t whF[8*3*4*64*4];   // w_hh A-frags: [gatewave][r/z/n][kstep][lane][4w]
  uint32_t whdF[2*4*64*4];    // W_head^T A-frags: [otile][kstep][lane][4w]
  uint32_t hF[4*64*4];        // h B-frags: [kstep][lane][4w]
  uint32_t liftF[64*4];       // lift B-frags: [lane][4w]
  float theta[8*20];          // [batch][o] (+pad slot o=19, kept == 0)
  float bh[20];               // b_head (+pad 0)
  float2 wl[10*16];           // W_lift pairs [row0..8 = W_lift, row9 = b_lift][col]
};

__global__ __launch_bounds__(NTHREADS)
void fullmodel_rnn(const float* __restrict__ y0,
                   const float* __restrict__ u_seq,
                   const float* __restrict__ dt_seq,
                   const float* __restrict__ y_seq,
                   const float* __restrict__ W_lift,
                   const float* __restrict__ b_lift,
                   const float* __restrict__ w_ih,
                   const float* __restrict__ w_hh,
                   const float* __restrict__ b_ih,
                   const float* __restrict__ b_hh,
                   const float* __restrict__ W_head,
                   const float* __restrict__ b_head,
                   const float* __restrict__ u2y,
                   const int*  __restrict__ tf_every_p,
                   float* __restrict__ out,
                   int K, int theta_off)
{
  extern __shared__ __align__(16) char smem_raw[];
  Smem& S = *reinterpret_cast<Smem*>(smem_raw);

  const int tid  = threadIdx.x;
  const int wid  = tid >> 6;
  const int lane = tid & 63;
  const int q    = lane >> 4;
  const int col  = lane & 15;
  const int bg0  = blockIdx.x * NB;
  const int tf_every = tf_every_p[0];
  const bool gatew = (wid < 8);

  // ---- init: build swizzled fragment tables in LDS ----
  for (int f = tid; f < 8*3*4*64; f += NTHREADS) {      // whF
    int l = f & 63, idx = f >> 6;
    int s = idx & 3; idx >>= 2;
    int g = idx % 3, w = idx / 3;
    int row = 128*g + 16*w + (l & 15);
    int k0 = 32*s + 8*(l >> 4);
    const float* p = w_hh + (size_t)row*HID + k0;
    uint32_t* d = S.whF + (size_t)f*4;
    d[0]=pk(p[0],p[1]); d[1]=pk(p[2],p[3]); d[2]=pk(p[4],p[5]); d[3]=pk(p[6],p[7]);
  }
  for (int f = tid; f < 2*4*64; f += NTHREADS) {        // whdF
    int l = f & 63, idx = f >> 6;
    int s = idx & 3, T = idx >> 2;
    int o = 16*T + (l & 15);
    int k0 = 32*s + 8*(l >> 4);
    uint32_t* d = S.whdF + (size_t)f*4;
    if (o < NTH) {
#pragma unroll
      for (int c=0;c<4;++c)
        d[c] = pk(W_head[(size_t)(k0+2*c)*NTH + o], W_head[(size_t)(k0+2*c+1)*NTH + o]);
    } else {
#pragma unroll
      for (int c=0;c<4;++c) d[c] = 0u;
    }
  }
  for (int f = tid; f < 4*64*4; f += NTHREADS) S.hF[f] = 0u;
  for (int f = tid; f < 64*4;   f += NTHREADS) S.liftF[f] = 0u;
  if (tid < 8)  S.theta[tid*20 + 19] = 0.f;             // pad slot == 0
  if (tid < 20) S.bh[tid] = (tid < NTH) ? b_head[tid] : 0.f;
  if (tid < 160) {
    const int r = tid >> 4, c = tid & 15;
    float2 w;
    if (r < 9) { w.x = W_lift[r*32 + 2*c]; w.y = W_lift[r*32 + 2*c + 1]; }
    else       { w.x = b_lift[2*c];        w.y = b_lift[2*c + 1]; }
    S.wl[tid] = w;
  }

  // ---- hoisted hot LDS pointers ----
  const uint32_t* hf_p  = &S.hF[lane*4];               // + 256*ss per kstep
  const uint32_t* lf_p  = &S.liftF[lane*4];
  const uint32_t* whp   = S.whF + ((size_t)wid*12*64 + lane)*4;   // + (g*4+ss)*256
  const uint32_t* whdp  = S.whdF + (size_t)lane*4;                // + (T*4+ss)*256

  // ---- gate-wave registers (3 w_ih A-frags = 12 VGPRs, safe under 84) ----
  float bsumR[4], bsumZ[4], bihn_[4], bhhn_[4], h_old[4];
  short8 wir, wiz, win;
  if (gatew) {
    const int rowR = 16*wid + col, kq = 8*q;
    wir = ldfrag(w_ih + (size_t)rowR*LIFT + kq);
    wiz = ldfrag(w_ih + (size_t)(128+rowR)*LIFT + kq);
    win = ldfrag(w_ih + (size_t)(256+rowR)*LIFT + kq);
#pragma unroll
    for (int r2=0;r2<4;++r2) {
      const int i0 = 16*wid + 4*q + r2;
      bsumR[r2] = b_ih[i0]     + b_hh[i0];
      bsumZ[r2] = b_ih[128+i0] + b_hh[128+i0];
      bihn_[r2] = b_ih[256+i0];
      bhhn_[r2] = b_hh[256+i0];
      h_old[r2] = 0.f;
    }
  }

  // ---- theta/RK4-wave registers ----
  const int base_b = (wid == 9) ? 4 : 0;
  const int b_loc = lane / NSP, rs = lane - NSP*b_loc;
  const bool rk_lane = (!gatew) && (lane < 52);
  const int bl8 = base_b + b_loc;
  const int gb = bg0 + (rk_lane ? bl8 : 0);
  const int gbL = bg0 + base_b + (lane >> 4);   // lift-gather batch (16-lane groups)
  const bool obs = rk_lane && (rs % 3 == 0);
  const int ro = rs / 3;
  float y_reg=0.f, f_src=0.f;
  float u2yv[4]={0,0,0,0};
  uint32_t pm=0, p0=0, pp=0;                    // packed theta indices rows rs-1,rs,rs+1
  int am1=0, ap1=0, am2=0, ap2=0, tfc=1;        // clamped bpermute addrs (x4)
  // 1-iter-ahead prefetch regs (direct per-lane loads replace bpermutes)
  float dt_c=0.f, ysq_c=0.f;
  float4 ujc = {0,0,0,0};                       // u(s) for the RK4 jump (obs lanes)
  float* outT0 = out; float* outY = out;
  if (!gatew) {
    outT0 = out + (size_t)theta_off + ((size_t)(bg0+col))*K*NTH + 4*q;
    __builtin_amdgcn_s_setprio(2);   // theta chain is the epoch critical path
  }
  if (rk_lane) {
    pm = c_pk2[rs]; p0 = c_pk2[rs+1]; pp = c_pk2[rs+2];
    // clamped neighbor addresses; cross-batch / clamped reads are killed by
    // structurally-zero coefficients (boundary rows of A / A^2)
    am1 = 4 * ((lane >= 1)  ? (lane - 1) : 0);
    am2 = 4 * ((lane >= 2)  ? (lane - 2) : 0);
    ap1 = 4 * ((lane <= 50) ? (lane + 1) : 51);
    ap2 = 4 * ((lane <= 49) ? (lane + 2) : 51);
    y_reg = 0.01f + (obs ? y0[gb*5 + ro] : 0.f);
    if (obs) { for (int d=0;d<4;++d) u2yv[d] = u2y[d*5 + ro]; }
    f_src = y_reg;                   // feat(0) y-part (mask(0)=false)
    outY = out + ((size_t)gb*K)*5 + ro;
  }
  sync_lds();

  // ================= main loop: K+1 iterations, 2 barriers each ============
  // Iteration k: gate waves compute h_state(k+1); theta waves finish step k-1
  // (theta(k-1), y(k-1), outputs) and produce lift(k) (feat via shuffles).
  for (int k = 0; k <= K; ++k) {
    f32x4 accR={0,0,0,0}, accZ={0,0,0,0}, accNH={0,0,0,0};

    if (gatew) {
      if (k < K) {
        // ---- Phase 1 (gate): gh for r,z,n — A-frags from LDS (hoisted ptr) --
        FragU h0,h1,h2,h3;
        h0.u = *reinterpret_cast<const uint4*>(hf_p);
        h1.u = *reinterpret_cast<const uint4*>(hf_p + 256);
        h2.u = *reinterpret_cast<const uint4*>(hf_p + 512);
        h3.u = *reinterpret_cast<const uint4*>(hf_p + 768);
#pragma unroll
        for (int ss=0; ss<4; ++ss) {
          FragU ar,az,an;
          ar.u = *reinterpret_cast<const uint4*>(whp + (0*4+ss)*256);
          az.u = *reinterpret_cast<const uint4*>(whp + (1*4+ss)*256);
          an.u = *reinterpret_cast<const uint4*>(whp + (2*4+ss)*256);
          const short8 hb = (ss==0)?h0.s:(ss==1)?h1.s:(ss==2)?h2.s:h3.s;
          accR  = __builtin_amdgcn_mfma_f32_16x16x32_bf16(ar.s, hb, accR, 0,0,0);
          accZ  = __builtin_amdgcn_mfma_f32_16x16x32_bf16(az.s, hb, accZ, 0,0,0);
          accNH = __builtin_amdgcn_mfma_f32_16x16x32_bf16(an.s, hb, accNH, 0,0,0);
        }
      }
    } else {
      // ---- Phase 1 (theta waves): step s = k-1 tail + lift(k) ----
      // prefetch: issued at top (loads fly across barriers / under MFMA+RK4).
      float dt_p=0.f, ysq_p=0.f;
      float4 ujp = {0,0,0,0}, ul = {0,0,0,0};
      if (k < K) {
        if (rk_lane) {
          dt_p = dt_seq[(size_t)gb*K + k];
          ujp  = *reinterpret_cast<const float4*>(u_seq + ((size_t)gb*K + k)*4);
          if (obs) ysq_p = y_seq[((size_t)gb*K + k)*5 + ro];
        }
        ul = *reinterpret_cast<const float4*>(u_seq + ((size_t)gbL*K + k)*4);
      }
      if (k >= 1) {
        // y-jump + 4 parallel neighbor bpermutes issued EARLY (theta-
        // independent); latency hides under the head MFMA below.
        float yj=0.f, y_m1=0.f, y_p1=0.f, y_m2=0.f, y_p2=0.f;
        if (rk_lane) {
          yj = y_reg;
          if (obs) yj += ujc.x*u2yv[0] + ujc.y*u2yv[1] + ujc.z*u2yv[2] + ujc.w*u2yv[3];
          y_m1 = bperm(am1, yj); y_p1 = bperm(ap1, yj);
          y_m2 = bperm(am2, yj); y_p2 = bperm(ap2, yj);
        }
        // head MFMA — A-frags from LDS (hoisted ptr)
        f32x4 at0={0,0,0,0}, at1={0,0,0,0};
        FragU h0,h1,h2,h3;
        h0.u = *reinterpret_cast<const uint4*>(hf_p);
        h1.u = *reinterpret_cast<const uint4*>(hf_p + 256);
        h2.u = *reinterpret_cast<const uint4*>(hf_p + 512);
        h3.u = *reinterpret_cast<const uint4*>(hf_p + 768);
#pragma unroll
        for (int ss=0; ss<4; ++ss) {
          FragU a0,a1;
          a0.u = *reinterpret_cast<const uint4*>(whdp + (0*4+ss)*256);
          a1.u = *reinterpret_cast<const uint4*>(whdp + (1*4+ss)*256);
          const short8 hb = (ss==0)?h0.s:(ss==1)?h1.s:(ss==2)?h2.s:h3.s;
          at0 = __builtin_amdgcn_mfma_f32_16x16x32_bf16(a0.s, hb, at0, 0,0,0);
          at1 = __builtin_amdgcn_mfma_f32_16x16x32_bf16(a1.s, hb, at1, 0,0,0);
        }
        if (col >= base_b && col < base_b + 4) {
          const f32x4 bh0 = *reinterpret_cast<const f32x4*>(&S.bh[4*q]);
          f32x4 th0;
#pragma unroll
          for (int r2=0;r2<4;++r2) th0[r2] = 0.001f + 1.999f*sigm(at0[r2] + bh0[r2]);
          *reinterpret_cast<f32x4*>(&S.theta[col*20 + 4*q]) = th0;
          outT0[0]=th0[0]; outT0[1]=th0[1]; outT0[2]=th0[2]; outT0[3]=th0[3];
          if (q == 0) {                    // tile1: o = 16..18 (+ zero pad 19)
            const f32x4 bh1 = *reinterpret_cast<const f32x4*>(&S.bh[16]);
            f32x4 th1;
#pragma unroll
            for (int r2=0;r2<4;++r2) th1[r2] = 0.001f + 1.999f*sigm(at1[r2] + bh1[r2]);
            outT0[16]=th1[0]; outT0[17]=th1[1]; outT0[18]=th1[2];
            th1[3] = 0.f;                  // keep pad slot 19 == 0 for index pads
            *reinterpret_cast<f32x4*>(&S.theta[col*20 + 16]) = th1;
          }
        }
        // ---- polynomial RK4 (exact for linear RHS):
        //   y+ = y + dt(Ay) + dt^2/2 (A^2 y) + dt^3/6 (A^3 y) + dt^4/24 (A^4 y)
        // After the theta write: 12 parallel coeff reads -> z2 -> 4 parallel
        // bpermutes -> s3/s4. Two serial cross-lane steps vs R2's five.
        if (rk_lane) {
          const float dtv = dt_c;
          const float* thb = S.theta + bl8*20;
          // own row (a0,b0,c0) + neighbor rows of A — 12 parallel LDS reads
          const float a_m = thb[pm & 31];
          const float b_m = -(thb[(pm>>5) & 31] + thb[(pm>>10) & 31]);
          const float c_m = thb[(pm>>15) & 31];
          const float a0  = thb[p0 & 31];
          const float b0  = -(thb[(p0>>5) & 31] + thb[(p0>>10) & 31]);
          const float c0  = thb[(p0>>15) & 31];
          const float a_p = thb[pp & 31];
          const float b_p = -(thb[(pp>>5) & 31] + thb[(pp>>10) & 31]);
          const float c_p = thb[(pp>>15) & 31];
          // A^2 row of rs (5-banded)
          const float r2m2 = a0*a_m;
          const float r2m1 = a0*b_m + b0*a0;
          const float r2c  = a0*c_m + b0*b0 + c0*a_p;
          const float r2p1 = b0*c0 + c0*b_p;
          const float r2p2 = c0*c_p;
          // s1 = (A y)[rs], z2 = (A^2 y)[rs]
          const float s1 = a0*y_m1 + b0*yj + c0*y_p1;
          const float z2 = r2m2*y_m2 + r2m1*y_m1 + r2c*yj + r2p1*y_p1 + r2p2*y_p2;
          // z2 neighbor exchange -> (A^3 y) via A-row, (A^4 y) via A^2-row
          const float z_m1 = bperm(am1, z2), z_p1 = bperm(ap1, z2);
          const float z_m2 = bperm(am2, z2), z_p2 = bperm(ap2, z2);
          const float s3 = a0*z_m1 + b0*z2 + c0*z_p1;
          const float s4 = r2m2*z_m2 + r2m1*z_m1 + r2c*z2 + r2p1*z_p1 + r2p2*z_p2;
          const float dt2 = dtv*dtv;
          float acc = fmaf(dtv, s1, yj);
          acc = fmaf(dt2*0.5f, z2, acc);
          acc = fmaf(dt2*dtv*(1.f/6.f), s3, acc);
          acc = fmaf(dt2*dt2*(1.f/24.f), s4, acc);
          const float yn = fmaxf(acc, 0.f);
          y_reg = yn;
          if (obs) *outY = yn;
          if (k < K) {
            const bool m_next = (tfc == tf_every);   // == (k % tf_every == 0)
            tfc = m_next ? 1 : (tfc + 1);
            if (obs) f_src = m_next ? ysq_c : yn;    // feat(k) y-part source
          }
        }
        outT0 += NTH; outY += 5;
      }
      if (k < K) {
        // lift(k): u-part from per-lane prefetched ul; y-part via 5 bpermutes;
        // W_lift/b_lift pairs from LDS (reads overlap the shuffles)
        const int g4 = NSP*(lane >> 4);
        const float2 w0 = S.wl[0*16+col], w1 = S.wl[1*16+col], w2 = S.wl[2*16+col];
        const float2 w3 = S.wl[3*16+col], w4 = S.wl[4*16+col], w5 = S.wl[5*16+col];
        const float2 w6 = S.wl[6*16+col], w7 = S.wl[7*16+col], w8 = S.wl[8*16+col];
        const float2 w9 = S.wl[9*16+col];
        const float fy0 = __shfl(f_src, g4+0), fy1 = __shfl(f_src, g4+3);
        const float fy2 = __shfl(f_src, g4+6), fy3 = __shfl(f_src, g4+9);
        const float fy4 = __shfl(f_src, g4+12);
        float a = w9.x + ul.x*w0.x + ul.y*w1.x + ul.z*w2.x + ul.w*w3.x
                       + fy0*w4.x + fy1*w5.x + fy2*w6.x + fy3*w7.x + fy4*w8.x;
        float b = w9.y + ul.x*w0.y + ul.y*w1.y + ul.z*w2.y + ul.w*w3.y
                       + fy0*w4.y + fy1*w5.y + fy2*w6.y + fy3*w7.y + fy4*w8.y;
        const float va = a*sigm(a), vb = b*sigm(b);
        const int bL = base_b + (lane >> 4);
        S.liftF[(col>>2)*64 + bL*4 + (col&3)] = pk(va, vb);
      }
      dt_c = dt_p; ysq_c = ysq_p; ujc = ujp;          // rotate prefetch
    }
    sync_lds();                                       // B1: lift(k) visible

    if (gatew && k < K) {
      // ---- Phase 2 (gate): gx via register A-frags; h-update; write hF ----
      FragU lf; lf.u = *reinterpret_cast<const uint4*>(lf_p);
      accR = __builtin_amdgcn_mfma_f32_16x16x32_bf16(wir, lf.s, accR, 0,0,0);
      accZ = __builtin_amdgcn_mfma_f32_16x16x32_bf16(wiz, lf.s, accZ, 0,0,0);
      f32x4 z4 = {0,0,0,0};
      f32x4 accNX = __builtin_amdgcn_mfma_f32_16x16x32_bf16(win, lf.s, z4, 0,0,0);
      float hn[4];
#pragma unroll
      for (int r2=0;r2<4;++r2) {
        const float rg = sigm(accR[r2] + bsumR[r2]);
        const float zg = sigm(accZ[r2] + bsumZ[r2]);
        const float nx = accNX[r2] + bihn_[r2];
        const float nh = accNH[r2] + bhhn_[r2];
        const float e  = __expf(2.f*(nx + rg*nh));
        const float ng = 1.f - 2.f/(e + 1.f);
        hn[r2] = (1.f - zg)*ng + zg*h_old[r2];
        h_old[r2] = hn[r2];
      }
      // scatter h_new into B-frag layout: i = 16*wid + 4*q + r2, n = col
      const int word = (wid>>1)*256 + ((((2*wid)+(q>>1))&3)*16 + col)*4 + 2*(q&1);
      *reinterpret_cast<uint2*>(&S.hF[word]) = make_uint2(pk(hn[0],hn[1]), pk(hn[2],hn[3]));
    }
    sync_lds();                                       // B2: h(k+1) visible
  }
}

extern "C" void kernel_launch(void* const* d_in, const int* in_sizes, int n_in,
                              void* d_out, int out_size, void* d_ws, size_t ws_size,
                              hipStream_t stream) {
  const float* y0     = (const float*)d_in[0];
  const float* u_seq  = (const float*)d_in[1];
  const float* dt_seq = (const float*)d_in[2];
  const float* y_seq  = (const float*)d_in[3];
  const float* W_lift = (const float*)d_in[4];
  const float* b_lift = (const float*)d_in[5];
  const float* w_ih   = (const float*)d_in[6];
  const float* w_hh   = (const float*)d_in[7];
  const float* b_ih   = (const float*)d_in[8];
  const float* b_hh   = (const float*)d_in[9];
  const float* W_head = (const float*)d_in[10];
  const float* b_head = (const float*)d_in[11];
  const float* u2y    = (const float*)d_in[12];
  const int*   tfe    = (const int*)d_in[13];
  float* out = (float*)d_out;

  const int B = in_sizes[0] / 5;            // 2048
  const int K = in_sizes[2] / B;            // 256
  const int theta_off = B * K * 5;

  (void)hipFuncSetAttribute((const void*)fullmodel_rnn,
                            hipFuncAttributeMaxDynamicSharedMemorySize,
                            (int)sizeof(Smem));

  dim3 grid(B / NB), block(NTHREADS);
  hipLaunchKernelGGL(fullmodel_rnn, grid, block, sizeof(Smem), stream,
                     y0, u_seq, dt_seq, y_seq, W_lift, b_lift, w_ih, w_hh,
                     b_ih, b_hh, W_head, b_head, u2y, tfe, out, K, theta_off);
}

// Round 11
// 646.228 us; speedup vs baseline: 1.0563x; 1.0563x over previous
//
#include <hip/hip_runtime.h>
#include <cstddef>
#include <cstdint>

#define NB 8
#define NTHREADS 640        // 8 gate waves + 2 theta/RK4 waves
#define HID 128
#define LIFT 32
#define NSP 13
#define NTH 19

typedef __attribute__((ext_vector_type(8))) short short8;
typedef __attribute__((ext_vector_type(4))) float f32x4;

// Neighbor-form RK4 tables. The chain network only couples rs-1, rs, rs+1:
//   dy[rs] = cA*y[rs-1] + cB*y[rs] + cC*y[rs+1]
//   cA = th[kA]; cB = -(th[kB1] + th[kB2]); cC = th[kC]
// Absent terms are redirected to pad slot 19 of S.theta, which is kept == 0.
__device__ const int c_kA [13] = {19,0,1,2,3,4,5,6,7,8,9,10,11};
__device__ const int c_kB1[13] = {0,12,2,13,4,14,6,15,8,16,10,17,18};
__device__ const int c_kB2[13] = {19,1,19,3,19,5,19,7,19,9,19,11,19};
__device__ const int c_kC [13] = {12,19,13,19,14,19,15,19,16,19,17,18,19};

__device__ __forceinline__ uint32_t pk(float a, float b) {
  uint32_t ua = __float_as_uint(a), ub = __float_as_uint(b);
  ua = (ua + 0x7FFFu + ((ua >> 16) & 1u)) >> 16;
  ub = (ub + 0x7FFFu + ((ub >> 16) & 1u)) >> 16;
  return ua | (ub << 16);
}
__device__ __forceinline__ float sigm(float a) { return 1.f/(1.f + __expf(-a)); }

// LDS-only barrier: drain this wave's LDS ops, then s_barrier. Does NOT wait
// vmcnt(0): global output stores / prefetch loads stay in flight across it.
__device__ __forceinline__ void sync_lds() {
  __builtin_amdgcn_sched_barrier(0);
  asm volatile("s_waitcnt lgkmcnt(0)" ::: "memory");
  __builtin_amdgcn_s_barrier();
  __builtin_amdgcn_sched_barrier(0);
}

// One RHS eval: 2 fixed-neighbor bpermutes + 3-term FMA.
__device__ __forceinline__ float rhs3(int am1, int ap1, float cA, float cB,
                                      float cC, float yc) {
  const float ym1 = __int_as_float(__builtin_amdgcn_ds_bpermute(am1, __float_as_int(yc)));
  const float yp1 = __int_as_float(__builtin_amdgcn_ds_bpermute(ap1, __float_as_int(yc)));
  return fmaf(cA, ym1, fmaf(cB, yc, cC * yp1));
}

union FragU { uint4 u; short8 s; };
// pack 8 consecutive floats into a bf16 short8 fragment (register-resident)
__device__ __forceinline__ short8 ldfrag(const float* p) {
  FragU t;
  const float4 a = *reinterpret_cast<const float4*>(p);
  const float4 b = *reinterpret_cast<const float4*>(p+4);
  t.u = make_uint4(pk(a.x,a.y), pk(a.z,a.w), pk(b.x,b.y), pk(b.z,b.w));
  return t.s;
}

// SESSION FLOOR NOTE (R0-R10): the per-step serial chain
//   head-MFMA -> sigm -> RK4 (4 cross-lane stages) -> lift -> B1 ->
//   gx-MFMA -> h-combine -> B2
// is algorithmically irreducible (y(k)->feat(k)->h(k+1)->theta(k)->y(k+1)
// is one dependency per step). Measured invariances: gate-phase LDS traffic
// is off-path (R3/R5: +-96KB/iter = 0%); serial-hop cuts move <+-6% (R9/R10);
// co-residency cannot beat K x chain-latency and is blocked anyway by the
// 16-wave cap at VGPR>64 (R4/R5). Weights stay in LDS as swizzled MFMA
// A-frags (84-VGPR spill cap: R1/R3/R4). This is the verified champion
// configuration: 597us dispatch.
struct Smem {
  uint32_t whF[8*3*4*64*4];   // w_hh A-frags: [gatewave][r/z/n][kstep][lane][4w]
  uint32_t whdF[2*4*64*4];    // W_head^T A-frags: [otile][kstep][lane][4w]
  uint32_t hF[4*64*4];        // h B-frags: [kstep][lane][4w]
  uint32_t liftF[64*4];       // lift B-frags: [lane][4w]
  float theta[8*20];          // [batch][o] (+pad slot o=19, kept == 0)
};

__global__ __launch_bounds__(NTHREADS)
void fullmodel_rnn(const float* __restrict__ y0,
                   const float* __restrict__ u_seq,
                   const float* __restrict__ dt_seq,
                   const float* __restrict__ y_seq,
                   const float* __restrict__ W_lift,
                   const float* __restrict__ b_lift,
                   const float* __restrict__ w_ih,
                   const float* __restrict__ w_hh,
                   const float* __restrict__ b_ih,
                   const float* __restrict__ b_hh,
                   const float* __restrict__ W_head,
                   const float* __restrict__ b_head,
                   const float* __restrict__ u2y,
                   const int*  __restrict__ tf_every_p,
                   float* __restrict__ out,
                   int K, int theta_off)
{
  extern __shared__ __align__(16) char smem_raw[];
  Smem& S = *reinterpret_cast<Smem*>(smem_raw);

  const int tid  = threadIdx.x;
  const int wid  = tid >> 6;
  const int lane = tid & 63;
  const int q    = lane >> 4;
  const int col  = lane & 15;
  const int bg0  = blockIdx.x * NB;
  const int tf_every = tf_every_p[0];
  const bool gatew = (wid < 8);

  // ---- init: build swizzled fragment tables in LDS ----
  for (int f = tid; f < 8*3*4*64; f += NTHREADS) {      // whF
    int l = f & 63, idx = f >> 6;
    int s = idx & 3; idx >>= 2;
    int g = idx % 3, w = idx / 3;
    int row = 128*g + 16*w + (l & 15);
    int k0 = 32*s + 8*(l >> 4);
    const float* p = w_hh + (size_t)row*HID + k0;
    uint32_t* d = S.whF + (size_t)f*4;
    d[0]=pk(p[0],p[1]); d[1]=pk(p[2],p[3]); d[2]=pk(p[4],p[5]); d[3]=pk(p[6],p[7]);
  }
  for (int f = tid; f < 2*4*64; f += NTHREADS) {        // whdF
    int l = f & 63, idx = f >> 6;
    int s = idx & 3, T = idx >> 2;
    int o = 16*T + (l & 15);
    int k0 = 32*s + 8*(l >> 4);
    uint32_t* d = S.whdF + (size_t)f*4;
    if (o < NTH) {
#pragma unroll
      for (int c=0;c<4;++c)
        d[c] = pk(W_head[(size_t)(k0+2*c)*NTH + o], W_head[(size_t)(k0+2*c+1)*NTH + o]);
    } else {
#pragma unroll
      for (int c=0;c<4;++c) d[c] = 0u;
    }
  }
  for (int f = tid; f < 4*64*4; f += NTHREADS) S.hF[f] = 0u;
  for (int f = tid; f < 64*4;   f += NTHREADS) S.liftF[f] = 0u;
  if (tid < 8) S.theta[tid*20 + 19] = 0.f;              // pad slot == 0

  // ---- hoisted hot LDS pointers ----
  const uint32_t* hf_p  = &S.hF[lane*4];               // + 256*ss per kstep
  const uint32_t* lf_p  = &S.liftF[lane*4];
  const uint32_t* whp   = S.whF + ((size_t)wid*12*64 + lane)*4;   // + (g*4+ss)*256
  const uint32_t* whdp  = S.whdF + (size_t)lane*4;                // + (T*4+ss)*256

  // ---- gate-wave registers (3 w_ih A-frags = 12 VGPRs, safe under 84) ----
  float bsumR[4], bsumZ[4], bihn_[4], bhhn_[4], h_old[4];
  short8 wir, wiz, win;
  if (gatew) {
    const int rowR = 16*wid + col, kq = 8*q;
    wir = ldfrag(w_ih + (size_t)rowR*LIFT + kq);
    wiz = ldfrag(w_ih + (size_t)(128+rowR)*LIFT + kq);
    win = ldfrag(w_ih + (size_t)(256+rowR)*LIFT + kq);
#pragma unroll
    for (int r2=0;r2<4;++r2) {
      const int i0 = 16*wid + 4*q + r2;
      bsumR[r2] = b_ih[i0]     + b_hh[i0];
      bsumZ[r2] = b_ih[128+i0] + b_hh[128+i0];
      bihn_[r2] = b_ih[256+i0];
      bhhn_[r2] = b_hh[256+i0];
      h_old[r2] = 0.f;
    }
  }

  // ---- theta/RK4-wave registers ----
  float bhd[2][4] = {{0,0,0,0},{0,0,0,0}};
  float wa0=0,wa1=0,wa2=0,wa3=0,wa4=0,wa5=0,wa6=0,wa7=0,wa8=0;
  float wb0=0,wb1=0,wb2=0,wb3=0,wb4=0,wb5=0,wb6=0,wb7=0,wb8=0;
  float blA=0.f, blB=0.f;
  const int base_b = (wid == 9) ? 4 : 0;
  const int b_loc = lane / NSP, rs = lane - NSP*b_loc;
  const bool rk_lane = (!gatew) && (lane < 52);
  const int bl8 = base_b + b_loc;
  const int gb = bg0 + (rk_lane ? bl8 : 0);
  const int gbL = bg0 + base_b + (lane >> 4);   // lift-gather batch (16-lane groups)
  const bool obs = rk_lane && (rs % 3 == 0);
  const int ro = rs / 3;
  float y_reg=0.f, f_src=0.f;
  float u2yv[4]={0,0,0,0};
  int kA_=0,kB1_=0,kB2_=0,kC_=0;
  int am1=0, ap1=0, tfc=1;
  // 1-iter-ahead prefetch regs (direct per-lane loads replace bpermutes)
  float dt_c=0.f, ysq_c=0.f;
  float4 ujc = {0,0,0,0};                       // u(s) for the RK4 jump (obs lanes)
  float* outT0 = out; float* outY = out;
  if (!gatew) {
#pragma unroll
    for (int T=0;T<2;++T)
#pragma unroll
      for (int r2=0;r2<4;++r2) {
        const int o = 16*T + 4*q + r2;
        bhd[T][r2] = (o < NTH) ? b_head[o] : 0.f;
      }
    // W_lift columns for this lane's two lift outputs, in registers
    const int li = 2*col;
    wa0=W_lift[0*32+li]; wa1=W_lift[1*32+li]; wa2=W_lift[2*32+li];
    wa3=W_lift[3*32+li]; wa4=W_lift[4*32+li]; wa5=W_lift[5*32+li];
    wa6=W_lift[6*32+li]; wa7=W_lift[7*32+li]; wa8=W_lift[8*32+li];
    wb0=W_lift[0*32+li+1]; wb1=W_lift[1*32+li+1]; wb2=W_lift[2*32+li+1];
    wb3=W_lift[3*32+li+1]; wb4=W_lift[4*32+li+1]; wb5=W_lift[5*32+li+1];
    wb6=W_lift[6*32+li+1]; wb7=W_lift[7*32+li+1]; wb8=W_lift[8*32+li+1];
    blA = b_lift[li]; blB = b_lift[li+1];
    outT0 = out + (size_t)theta_off + ((size_t)(bg0+col))*K*NTH + 4*q;
    __builtin_amdgcn_s_setprio(2);   // theta chain is the epoch critical path
  }
  if (rk_lane) {
    kA_ = c_kA[rs]; kB1_ = c_kB1[rs]; kB2_ = c_kB2[rs]; kC_ = c_kC[rs];
    am1 = 4 * ((lane > 0)  ? (lane - 1) : 0);    // clamp: edge coeff is 0
    ap1 = 4 * ((lane < 51) ? (lane + 1) : 51);
    y_reg = 0.01f + (obs ? y0[gb*5 + ro] : 0.f);
    if (obs) { for (int d=0;d<4;++d) u2yv[d] = u2y[d*5 + ro]; }
    f_src = y_reg;                   // feat(0) y-part (mask(0)=false)
    outY = out + ((size_t)gb*K)*5 + ro;
  }
  sync_lds();

  // ================= main loop: K+1 iterations, 2 barriers each ============
  // Iteration k: gate waves compute h_state(k+1); theta waves finish step k-1
  // (theta(k-1), y(k-1), outputs) and produce lift(k) (feat via shuffles).
  for (int k = 0; k <= K; ++k) {
    f32x4 accR={0,0,0,0}, accZ={0,0,0,0}, accNH={0,0,0,0};

    if (gatew) {
      if (k < K) {
        // ---- Phase 1 (gate): gh for r,z,n — A-frags from LDS (hoisted ptr) --
        FragU h0,h1,h2,h3;
        h0.u = *reinterpret_cast<const uint4*>(hf_p);
        h1.u = *reinterpret_cast<const uint4*>(hf_p + 256);
        h2.u = *reinterpret_cast<const uint4*>(hf_p + 512);
        h3.u = *reinterpret_cast<const uint4*>(hf_p + 768);
#pragma unroll
        for (int ss=0; ss<4; ++ss) {
          FragU ar,az,an;
          ar.u = *reinterpret_cast<const uint4*>(whp + (0*4+ss)*256);
          az.u = *reinterpret_cast<const uint4*>(whp + (1*4+ss)*256);
          an.u = *reinterpret_cast<const uint4*>(whp + (2*4+ss)*256);
          const short8 hb = (ss==0)?h0.s:(ss==1)?h1.s:(ss==2)?h2.s:h3.s;
          accR  = __builtin_amdgcn_mfma_f32_16x16x32_bf16(ar.s, hb, accR, 0,0,0);
          accZ  = __builtin_amdgcn_mfma_f32_16x16x32_bf16(az.s, hb, accZ, 0,0,0);
          accNH = __builtin_amdgcn_mfma_f32_16x16x32_bf16(an.s, hb, accNH, 0,0,0);
        }
      }
    } else {
      // ---- Phase 1 (theta waves): step s = k-1 tail + lift(k) ----
      // prefetch: issued at top (loads fly across barriers / under MFMA+RK4).
      // dt/uj/ysq are for NEXT iteration (rotated); ul is for THIS iter's lift.
      float dt_p=0.f, ysq_p=0.f;
      float4 ujp = {0,0,0,0}, ul = {0,0,0,0};
      if (k < K) {
        if (rk_lane) {
          dt_p = dt_seq[(size_t)gb*K + k];
          ujp  = *reinterpret_cast<const float4*>(u_seq + ((size_t)gb*K + k)*4);
          if (obs) ysq_p = y_seq[((size_t)gb*K + k)*5 + ro];
        }
        ul = *reinterpret_cast<const float4*>(u_seq + ((size_t)gbL*K + k)*4);
      }
      if (k >= 1) {
        // head MFMA — A-frags from LDS (hoisted ptr)
        f32x4 at0={0,0,0,0}, at1={0,0,0,0};
        FragU h0,h1,h2,h3;
        h0.u = *reinterpret_cast<const uint4*>(hf_p);
        h1.u = *reinterpret_cast<const uint4*>(hf_p + 256);
        h2.u = *reinterpret_cast<const uint4*>(hf_p + 512);
        h3.u = *reinterpret_cast<const uint4*>(hf_p + 768);
#pragma unroll
        for (int ss=0; ss<4; ++ss) {
          FragU a0,a1;
          a0.u = *reinterpret_cast<const uint4*>(whdp + (0*4+ss)*256);
          a1.u = *reinterpret_cast<const uint4*>(whdp + (1*4+ss)*256);
          const short8 hb = (ss==0)?h0.s:(ss==1)?h1.s:(ss==2)?h2.s:h3.s;
          at0 = __builtin_amdgcn_mfma_f32_16x16x32_bf16(a0.s, hb, at0, 0,0,0);
          at1 = __builtin_amdgcn_mfma_f32_16x16x32_bf16(a1.s, hb, at1, 0,0,0);
        }
        if (col >= base_b && col < base_b + 4) {
          // tile0: o = 4q..4q+3 — one aligned b128 LDS store + 4 global stores
          f32x4 th0;
#pragma unroll
          for (int r2=0;r2<4;++r2) th0[r2] = 0.001f + 1.999f*sigm(at0[r2] + bhd[0][r2]);
          *reinterpret_cast<f32x4*>(&S.theta[col*20 + 4*q]) = th0;
          outT0[0]=th0[0]; outT0[1]=th0[1]; outT0[2]=th0[2]; outT0[3]=th0[3];
          if (q == 0) {                    // tile1: o = 16..18 (+ zero pad 19)
            f32x4 th1;
#pragma unroll
            for (int r2=0;r2<4;++r2) th1[r2] = 0.001f + 1.999f*sigm(at1[r2] + bhd[1][r2]);
            outT0[16]=th1[0]; outT0[17]=th1[1]; outT0[18]=th1[2];
            th1[3] = 0.f;                  // keep pad slot 19 == 0 for RK4 tables
            *reinterpret_cast<f32x4*>(&S.theta[col*20 + 16]) = th1;
          }
        }
        // RK4 (wave-local; theta just written by this wave). All coefficient
        // inputs (dt, u-jump) are per-lane prefetched regs — no entry shuffles.
        if (rk_lane) {
          const float dtv = dt_c;
          const float* thp = S.theta + bl8*20;
          const float cA = thp[kA_];
          const float cB = -(thp[kB1_] + thp[kB2_]);
          const float cC = thp[kC_];
          float yj = y_reg;
          if (obs) yj += ujc.x*u2yv[0] + ujc.y*u2yv[1] + ujc.z*u2yv[2] + ujc.w*u2yv[3];
          float yc = yj;
          const float k1 = rhs3(am1, ap1, cA, cB, cC, yc);
          yc = fmaf(0.5f*dtv, k1, yj);
          const float k2 = rhs3(am1, ap1, cA, cB, cC, yc);
          yc = fmaf(0.5f*dtv, k2, yj);
          const float k3 = rhs3(am1, ap1, cA, cB, cC, yc);
          yc = fmaf(dtv, k3, yj);
          const float k4 = rhs3(am1, ap1, cA, cB, cC, yc);
          const float yn = fmaxf(fmaf(dtv*(1.f/6.f), k1 + 2.f*k2 + 2.f*k3 + k4, yj), 0.f);
          y_reg = yn;
          if (obs) *outY = yn;
          if (k < K) {
            const bool m_next = (tfc == tf_every);   // == (k % tf_every == 0)
            tfc = m_next ? 1 : (tfc + 1);
            if (obs) f_src = m_next ? ysq_c : yn;    // feat(k) y-part source
          }
        }
        outT0 += NTH; outY += 5;
      }
      if (k < K) {
        // lift(k): u-part from per-lane prefetched ul; y-part via 5 bpermutes
        const int g4 = NSP*(lane >> 4);
        const float fy0 = __shfl(f_src, g4+0), fy1 = __shfl(f_src, g4+3);
        const float fy2 = __shfl(f_src, g4+6), fy3 = __shfl(f_src, g4+9);
        const float fy4 = __shfl(f_src, g4+12);
        float a = blA + ul.x*wa0 + ul.y*wa1 + ul.z*wa2 + ul.w*wa3
                      + fy0*wa4 + fy1*wa5 + fy2*wa6 + fy3*wa7 + fy4*wa8;
        float b = blB + ul.x*wb0 + ul.y*wb1 + ul.z*wb2 + ul.w*wb3
                      + fy0*wb4 + fy1*wb5 + fy2*wb6 + fy3*wb7 + fy4*wb8;
        const float va = a*sigm(a), vb = b*sigm(b);
        const int bL = base_b + (lane >> 4);
        S.liftF[(col>>2)*64 + bL*4 + (col&3)] = pk(va, vb);
      }
      dt_c = dt_p; ysq_c = ysq_p; ujc = ujp;          // rotate prefetch
    }
    sync_lds();                                       // B1: lift(k) visible

    if (gatew && k < K) {
      // ---- Phase 2 (gate): gx via register A-frags; h-update; write hF ----
      FragU lf; lf.u = *reinterpret_cast<const uint4*>(lf_p);
      accR = __builtin_amdgcn_mfma_f32_16x16x32_bf16(wir, lf.s, accR, 0,0,0);
      accZ = __builtin_amdgcn_mfma_f32_16x16x32_bf16(wiz, lf.s, accZ, 0,0,0);
      f32x4 z4 = {0,0,0,0};
      f32x4 accNX = __builtin_amdgcn_mfma_f32_16x16x32_bf16(win, lf.s, z4, 0,0,0);
      float hn[4];
#pragma unroll
      for (int r2=0;r2<4;++r2) {
        const float rg = sigm(accR[r2] + bsumR[r2]);
        const float zg = sigm(accZ[r2] + bsumZ[r2]);
        const float nx = accNX[r2] + bihn_[r2];
        const float nh = accNH[r2] + bhhn_[r2];
        const float e  = __expf(2.f*(nx + rg*nh));
        const float ng = 1.f - 2.f/(e + 1.f);
        hn[r2] = (1.f - zg)*ng + zg*h_old[r2];
        h_old[r2] = hn[r2];
      }
      // scatter h_new into B-frag layout: i = 16*wid + 4*q + r2, n = col
      const int word = (wid>>1)*256 + ((((2*wid)+(q>>1))&3)*16 + col)*4 + 2*(q&1);
      *reinterpret_cast<uint2*>(&S.hF[word]) = make_uint2(pk(hn[0],hn[1]), pk(hn[2],hn[3]));
    }
    sync_lds();                                       // B2: h(k+1) visible
  }
}

extern "C" void kernel_launch(void* const* d_in, const int* in_sizes, int n_in,
                              void* d_out, int out_size, void* d_ws, size_t ws_size,
                              hipStream_t stream) {
  const float* y0     = (const float*)d_in[0];
  const float* u_seq  = (const float*)d_in[1];
  const float* dt_seq = (const float*)d_in[2];
  const float* y_seq  = (const float*)d_in[3];
  const float* W_lift = (const float*)d_in[4];
  const float* b_lift = (const float*)d_in[5];
  const float* w_ih   = (const float*)d_in[6];
  const float* w_hh   = (const float*)d_in[7];
  const float* b_ih   = (const float*)d_in[8];
  const float* b_hh   = (const float*)d_in[9];
  const float* W_head = (const float*)d_in[10];
  const float* b_head = (const float*)d_in[11];
  const float* u2y    = (const float*)d_in[12];
  const int*   tfe    = (const int*)d_in[13];
  float* out = (float*)d_out;

  const int B = in_sizes[0] / 5;            // 2048
  const int K = in_sizes[2] / B;            // 256
  const int theta_off = B * K * 5;

  (void)hipFuncSetAttribute((const void*)fullmodel_rnn,
                            hipFuncAttributeMaxDynamicSharedMemorySize,
                            (int)sizeof(Smem));

  dim3 grid(B / NB), block(NTHREADS);
  hipLaunchKernelGGL(fullmodel_rnn, grid, block, sizeof(Smem), stream,
                     y0, u_seq, dt_seq, y_seq, W_lift, b_lift, w_ih, w_hh,
                     b_ih, b_hh, W_head, b_head, u2y, tfe, out, K, theta_off);
}